// Round 10
// baseline (90.693 us; speedup 1.0000x reference)
//
#include <hip/hip_runtime.h>
#include <hip/hip_bf16.h>

#define IN_CAPS 32
#define OUT_CAPS 10
#define NOUT 160      // OUT_CAPS*OUT_DIM
#define KDIM 288
#define BATCH 4096
#define KSTEPS 9      // 288/32
#define CTILES 10     // 160/16
#define STR2 162      // LDS ushort stride for u rows in routing
#define APAD 296      // A-tile bf16 row stride: 592 B -> bank rot 20 mod 32 -> conflict-free

typedef __bf16 bf16x8 __attribute__((ext_vector_type(8)));
typedef float  f32x4  __attribute__((ext_vector_type(4)));
typedef __attribute__((address_space(1))) void as1_t;
typedef __attribute__((address_space(3))) void as3_t;

// ---------------------------------------------------------------------------
// prep_w: W f32 [32][288][160] -> bf16 in per-lane MFMA B-fragment order:
//   Wf[((n*9+ks)*10+ct)*512 + lane*8 + j] = W[n][ks*32+(lane>>4)*8+j][ct*16+(lane&15)]
// ---------------------------------------------------------------------------
__global__ __launch_bounds__(256) void prep_w(const float* __restrict__ W,
                                              __bf16* __restrict__ Wf) {
    int f = blockIdx.x * 256 + threadIdx.x;   // grid covers exactly 32*9*10*512
    int j    = f & 7;
    int l    = (f >> 3) & 63;
    int rest = f >> 9;
    int c    = rest % CTILES;
    int tnk  = rest / CTILES;
    int ks   = tnk % KSTEPS;
    int n    = tnk / KSTEPS;
    int k    = ks * 32 + (l >> 4) * 8 + j;
    int col  = c * 16 + (l & 15);
    Wf[f] = (__bf16)W[(n * KDIM + k) * NOUT + col];
}

// ---------------------------------------------------------------------------
// gemm_u v9: DRAM-PATTERN FIX. R2-R9 all read each (b,n) slice (1152 B = one
// DRAM page) in 9 temporal passes of 128 B -> ~9x page-activation overhead ->
// the invariant 1.5 TB/s plateau. Now: full-K A-tile staged ONCE per block
// with linear 32 B/thread sweeps (each slice read once, contiguously), bf16
// conversion at stage time, K-loop reads A as single ds_read_b128.
//  - 256 thr / 4 waves; 64 rows x one n; wave = 16 rows x 160 cols (acc=40).
//  - LDS: A 64x296 bf16 (37.9 KB) + B dbuf 2x10 KB = 58.4 KB -> 2 blocks/CU.
//  - B per-ks via global_load_lds (L2-resident Wf after gen 1).
// ---------------------------------------------------------------------------
__global__ __launch_bounds__(256) void gemm_u(const float* __restrict__ caps,
                                              const __bf16* __restrict__ Wf,
                                              uint4* __restrict__ up) {
    __shared__ __bf16 As[64 * APAD];      // 37,888 B
    __shared__ __bf16 Bs[2][5120];        // 20,480 B

    const int lin  = blockIdx.x;          // 0..2047, n-fastest
    const int n    = lin & 31;
    const int rb   = lin >> 5;            // 64-row group, 0..63
    const int t    = threadIdx.x;
    const int w    = t >> 6;
    const int lane = t & 63;
    const int lm   = lane & 15;
    const int lk   = lane >> 4;

    const __bf16* wb = Wf + (size_t)n * (KSTEPS * 5120);
    // B stage: 640 x 16B units; thread t covers units t, t+256, (t<128: t+512)
#define STAGE_B(ks, buf) do {                                                         \
    const __bf16* _s = wb + (size_t)(ks) * 5120;                                      \
    __builtin_amdgcn_global_load_lds((const as1_t*)(_s + t * 8),                      \
                                     (as3_t*)&Bs[buf][t * 8],         16, 0, 0);      \
    __builtin_amdgcn_global_load_lds((const as1_t*)(_s + (t + 256) * 8),              \
                                     (as3_t*)&Bs[buf][(t + 256) * 8], 16, 0, 0);      \
    if (t < 128)                                                                      \
        __builtin_amdgcn_global_load_lds((const as1_t*)(_s + (t + 512) * 8),          \
                                         (as3_t*)&Bs[buf][(t + 512) * 8], 16, 0, 0);  \
} while (0)

    // ---- A full-K stage: 64 slices x 1152 B, each read once, linearly ----
    // 32 B chunk c: row = c/36, pp = c%36; 2304 chunks over 256 threads.
    const float* abase = caps + ((size_t)rb * 64 * IN_CAPS + n) * KDIM;
    f32x4 raw[9][2];
#pragma unroll
    for (int i = 0; i < 9; ++i) {
        int c = t + i * 256;
        int row = c / 36, pp = c - row * 36;
        const float* src = abase + (size_t)row * (IN_CAPS * KDIM) + pp * 8;
        raw[i][0] = *(const f32x4*)src;
        raw[i][1] = *(const f32x4*)(src + 4);
    }
    STAGE_B(0, 0);
#pragma unroll
    for (int i = 0; i < 9; ++i) {
        int c = t + i * 256;
        int row = c / 36, pp = c - row * 36;
        bf16x8 v;
#pragma unroll
        for (int j = 0; j < 4; ++j) {
            v[j]     = (__bf16)raw[i][0][j];
            v[j + 4] = (__bf16)raw[i][1][j];
        }
        *(bf16x8*)&As[row * APAD + pp * 8] = v;
    }

    f32x4 acc[CTILES];
#pragma unroll
    for (int ct = 0; ct < CTILES; ++ct) acc[ct] = (f32x4){0.f, 0.f, 0.f, 0.f};

    __syncthreads();   // A tile + B[0] visible

    // ---- K-loop: A from LDS (1 ds_read_b128), B dbuf per ks ----
    const __bf16* arow = &As[(w * 16 + lm) * APAD];
#pragma unroll
    for (int ks = 0; ks < KSTEPS; ++ks) {
        if (ks + 1 < KSTEPS) STAGE_B(ks + 1, (ks + 1) & 1);
        bf16x8 a = *(const bf16x8*)(arow + ks * 32 + lk * 8);
        const __bf16* Bc = &Bs[ks & 1][lane * 8];
#pragma unroll
        for (int ct = 0; ct < CTILES; ++ct) {
            bf16x8 bfr = *(const bf16x8*)(Bc + ct * 512);
            acc[ct] = __builtin_amdgcn_mfma_f32_16x16x32_bf16(a, bfr, acc[ct], 0, 0, 0);
        }
        __syncthreads();   // drains stage(ks+1); protects Bs[ks&1] reuse
    }

    // ---- epilogue: permuted coalesced store (layout shared with routing):
    //   idx = (((n*128 + rw)*2 + mt)*5 + p)*64 + lane
    const int rw = rb * 2 + (w >> 1);
    const int mt = w & 1;
    const size_t cbase = ((((size_t)n * 128 + rw) * 2 + mt) * 5) * 64 + lane;
#pragma unroll
    for (int p = 0; p < 5; ++p) {
        bf16x8 pk;
#pragma unroll
        for (int j = 0; j < 8; ++j)
            pk[j] = (__bf16)acc[2 * p + (j >> 2)][j & 3];
        up[cbase + (size_t)p * 64] = __builtin_bit_cast(uint4, pk);
    }
#undef STAGE_B
}

// ---------------------------------------------------------------------------
// routing (unchanged from R4-R9): 4 consecutive batch rows per block.
// ---------------------------------------------------------------------------
__global__ __launch_bounds__(256) void routing(const uint4* __restrict__ up,
                                               const float* __restrict__ bbias,
                                               float* __restrict__ out) {
    __shared__ __bf16 ul[4][IN_CAPS * STR2];      // 41472 B
    __shared__ float  bl[4][IN_CAPS * OUT_CAPS];
    __shared__ float  cs[4][IN_CAPS * OUT_CAPS];
    __shared__ float  ss[4][NOUT];
    __shared__ float  vs[4][NOUT];
    __shared__ float  scale_s[4][16];

    const int t  = threadIdx.x;
    const int b0 = blockIdx.x * 4;
    const int rw = b0 >> 5;
    const int mt = (b0 >> 4) & 1;
    const int lk = (b0 >> 2) & 3;

    for (int c = t; c < 2560; c += 256) {
        int n   = c / 80;
        int rem = c - n * 80;
        int p   = rem >> 4;
        int lm  = rem & 15;
        size_t idx = ((((size_t)n * 128 + rw) * 2 + mt) * 5 + p) * 64 + lk * 16 + lm;
        bf16x8 v = __builtin_bit_cast(bf16x8, up[idx]);
#pragma unroll
        for (int j = 0; j < 8; ++j) {
            int ct = 2 * p + (j >> 2);
            int rr = j & 3;
            ul[rr][n * STR2 + ct * 16 + lm] = v[j];
        }
    }
    const int grp = t >> 6;
    const int g   = t & 63;
    for (int pp = g; pp < IN_CAPS * OUT_CAPS; pp += 64) bl[grp][pp] = bbias[pp];
    __syncthreads();

    for (int it = 0; it < 4; ++it) {
        if (it > 0) {
            for (int pp = g; pp < IN_CAPS * OUT_CAPS; pp += 64) {
                int n = pp & 31;
                int o = pp >> 5;
                float a = 0.f;
#pragma unroll
                for (int d = 0; d < 16; ++d)
                    a += (float)ul[grp][n * STR2 + o * 16 + d] * vs[grp][o * 16 + d];
                bl[grp][n * 10 + o] += a;
            }
            __syncthreads();
        }
        if (g < IN_CAPS) {
            float m = bl[grp][g * 10];
#pragma unroll
            for (int o = 1; o < 10; ++o) m = fmaxf(m, bl[grp][g * 10 + o]);
            float e[10];
            float sum = 0.f;
#pragma unroll
            for (int o = 0; o < 10; ++o) { e[o] = __expf(bl[grp][g * 10 + o] - m); sum += e[o]; }
            float inv = 1.0f / sum;
#pragma unroll
            for (int o = 0; o < 10; ++o) cs[grp][g * 10 + o] = e[o] * inv;
        }
        __syncthreads();
        for (int p = g; p < NOUT; p += 64) {
            int o = p >> 4;
            float a = 0.f;
#pragma unroll
            for (int nn = 0; nn < IN_CAPS; ++nn)
                a += cs[grp][nn * 10 + o] * (float)ul[grp][nn * STR2 + p];
            ss[grp][p] = a;
        }
        __syncthreads();
        if (g < OUT_CAPS) {
            float sq = 0.f;
#pragma unroll
            for (int d = 0; d < 16; ++d) { float x = ss[grp][g * 16 + d]; sq += x * x; }
            scale_s[grp][g] = sq / ((1.0f + sq) * sqrtf(sq));
        }
        __syncthreads();
        for (int p = g; p < NOUT; p += 64) vs[grp][p] = scale_s[grp][p >> 4] * ss[grp][p];
        __syncthreads();
    }

    for (int p = g; p < NOUT; p += 64)
        out[(size_t)(b0 + grp) * NOUT + p] = vs[grp][p];
}

// ---------------------------------------------------------------------------
extern "C" void kernel_launch(void* const* d_in, const int* in_sizes, int n_in,
                              void* d_out, int out_size, void* d_ws, size_t ws_size,
                              hipStream_t stream) {
    const float* caps  = (const float*)d_in[0];   // [4096][32][288]
    const float* W     = (const float*)d_in[1];   // [32][288][160]
    const float* bbias = (const float*)d_in[2];   // [32][10]
    float* out = (float*)d_out;                   // [4096][10][16]

    __bf16* Wf = (__bf16*)d_ws;                               // 2,949,120 B
    uint4*  up = (uint4*)((char*)d_ws + 2949120);             // 41,943,040 B

    prep_w<<<dim3(5760), dim3(256), 0, stream>>>(W, Wf);
    gemm_u<<<dim3(2048), dim3(256), 0, stream>>>(caps, Wf, up);
    routing<<<dim3(BATCH / 4), dim3(256), 0, stream>>>(up, bbias, out);
}